// Round 9
// baseline (331.117 us; speedup 1.0000x reference)
//
#include <hip/hip_runtime.h>
#include <hip/hip_cooperative_groups.h>

namespace cg = cooperative_groups;

#define C     128   // channels
#define CAP   128   // per-dest segment capacity (deg mean 64, sigma 8 -> 8 sigma)
#define GRID  512   // 2 blocks/CU x 256 CU -- comfortable co-residency margin
#define TPB   256
#define NPBT  16    // nodes per gemm tile

__device__ inline unsigned short f2bf(float v) {  // RNE float->bf16
    unsigned u = __float_as_uint(v);
    u = (u + 0x7fffu + ((u >> 16) & 1u)) >> 16;
    return (unsigned short)u;
}

// ==================== fused cooperative kernel ====================
__global__ __launch_bounds__(TPB, 2) void k_fused(
    const float* __restrict__ x, const int* __restrict__ row, const int* __restrict__ col,
    const float* __restrict__ W, const float* __restrict__ bias,
    int* __restrict__ cursor, unsigned short* __restrict__ list,
    unsigned short* __restrict__ g, int* __restrict__ tileCtr,
    float* __restrict__ out, int N, int E) {
    cg::grid_group grid = cg::this_grid();
    __shared__ float xs[NPBT][C];  // 8 KB
    __shared__ int stile;
    int tid = threadIdx.x;
    int gtid = blockIdx.x * TPB + tid;
    const int nthreads = GRID * TPB;

    // ---- phase 0: zero cursors + tile counter ----
    for (int i = gtid; i < N; i += nthreads) cursor[i] = 0;
    if (gtid == 0) *tileCtr = 0;
    grid.sync();

    // ---- phase 1: fill per-dest segments; cursor == in-degree ----
    int nq = E >> 2;
    for (int q = gtid; q < nq; q += nthreads) {
        int e = q * 4;
        int4 d4 = *(const int4*)(col + e);
        int4 s4 = *(const int4*)(row + e);
        int p0 = atomicAdd(&cursor[d4.x], 1);
        int p1 = atomicAdd(&cursor[d4.y], 1);
        int p2 = atomicAdd(&cursor[d4.z], 1);
        int p3 = atomicAdd(&cursor[d4.w], 1);
        if (p0 < CAP) list[d4.x * CAP + p0] = (unsigned short)s4.x;
        if (p1 < CAP) list[d4.y * CAP + p1] = (unsigned short)s4.y;
        if (p2 < CAP) list[d4.z * CAP + p2] = (unsigned short)s4.z;
        if (p3 < CAP) list[d4.w * CAP + p3] = (unsigned short)s4.w;
    }
    for (int e = (E & ~3) + gtid; e < E; e += nthreads) {
        int d = col[e];
        int p = atomicAdd(&cursor[d], 1);
        if (p < CAP) list[d * CAP + p] = (unsigned short)row[e];
    }
    grid.sync();

    // ---- phase 2: g[n][o] = bf16((x[n].W[o]) * rsqrt(deg+1)); work-queue tiles ----
    {
        int half = tid >> 7;       // 0/1
        int o = tid & 127;         // output channel
        const int ntiles = (N + NPBT - 1) / NPBT;
        const float4* Wr = (const float4*)(W + (size_t)o * C);
        const float4 z4 = {0.f, 0.f, 0.f, 0.f};
        for (;;) {
            if (tid == 0) stile = atomicAdd(tileCtr, 1);
            __syncthreads();
            int t = stile;
            __syncthreads();
            if (t >= ntiles) break;
            int n0 = t * NPBT;
            for (int qi = tid; qi < NPBT * C / 4; qi += TPB) {  // float4 staging
                int nd = qi >> 5, c4 = qi & 31;
                int n = n0 + nd;
                ((float4*)xs)[qi] = (n < N) ? ((const float4*)x)[(size_t)n * 32 + c4] : z4;
            }
            __syncthreads();
            float acc[8];
#pragma unroll
            for (int nd = 0; nd < 8; ++nd) acc[nd] = 0.0f;
            int nb = half * 8;
#pragma unroll 8
            for (int i = 0; i < C / 4; ++i) {
                float4 w = Wr[i];
#pragma unroll
                for (int nd = 0; nd < 8; ++nd) {
                    float4 xv = *(const float4*)&xs[nb + nd][i * 4];
                    acc[nd] += w.x * xv.x + w.y * xv.y + w.z * xv.z + w.w * xv.w;
                }
            }
            __syncthreads();  // xs consumed before next tile overwrites
#pragma unroll
            for (int nd = 0; nd < 8; ++nd) {
                int n = n0 + nb + nd;
                if (n < N) {
                    float dv = 1.0f / sqrtf((float)(cursor[n] + 1));
                    g[(size_t)n * C + o] = f2bf(acc[nd] * dv);
                }
            }
        }
    }
    grid.sync();

    // ---- phase 3: wave per dest; bf16x2 gather, fp32 register accumulation ----
    {
        const unsigned* gb = (const unsigned*)g;
        int lane = tid & 63;
        int wv0 = gtid >> 6;
        int nwaves = nthreads >> 6;
        for (int d = wv0; d < N; d += nwaves) {
            int deg = cursor[d];
            float dv = 1.0f / sqrtf((float)(deg + 1));
            int cnt = (deg < CAP) ? deg : CAP;
            const unsigned short* lp = list + (size_t)d * CAP;
            unsigned sv = gb[(size_t)d * 64 + lane];  // self-loop row
            float2 acc;
            acc.x = __uint_as_float(sv << 16);
            acc.y = __uint_as_float(sv & 0xffff0000u);
#define UNPACK_ADD(V) { acc.x += __uint_as_float((V) << 16); \
                        acc.y += __uint_as_float((V) & 0xffff0000u); }
            int j = 0;
            for (; j + 8 <= cnt; j += 8) {
                uint4 q = *(const uint4*)(lp + j);
                unsigned s0 = q.x & 0xffffu, s1 = q.x >> 16;
                unsigned s2 = q.y & 0xffffu, s3 = q.y >> 16;
                unsigned s4 = q.z & 0xffffu, s5 = q.z >> 16;
                unsigned s6 = q.w & 0xffffu, s7 = q.w >> 16;
                unsigned v0 = gb[(size_t)s0 * 64 + lane];
                unsigned v1 = gb[(size_t)s1 * 64 + lane];
                unsigned v2 = gb[(size_t)s2 * 64 + lane];
                unsigned v3 = gb[(size_t)s3 * 64 + lane];
                unsigned v4 = gb[(size_t)s4 * 64 + lane];
                unsigned v5 = gb[(size_t)s5 * 64 + lane];
                unsigned v6 = gb[(size_t)s6 * 64 + lane];
                unsigned v7 = gb[(size_t)s7 * 64 + lane];
                UNPACK_ADD(v0) UNPACK_ADD(v1) UNPACK_ADD(v2) UNPACK_ADD(v3)
                UNPACK_ADD(v4) UNPACK_ADD(v5) UNPACK_ADD(v6) UNPACK_ADD(v7)
            }
            for (; j < cnt; ++j) {
                unsigned s = lp[j];
                unsigned v = gb[(size_t)s * 64 + lane];
                UNPACK_ADD(v)
            }
#undef UNPACK_ADD
            int c2 = lane * 2;
            float2 bb = *(const float2*)(bias + c2);
            float2 o;
            o.x = dv * acc.x + bb.x;
            o.y = dv * acc.y + bb.y;
            *(float2*)(out + (size_t)d * C + c2) = o;
        }
    }
}

// ==================== fallback pipeline (R7 structure, CPAD=1) ====================
__global__ __launch_bounds__(256) void k_fill(const int* __restrict__ row,
                                              const int* __restrict__ col,
                                              int* __restrict__ cursor,
                                              unsigned short* __restrict__ list, int E) {
    int t = blockIdx.x * blockDim.x + threadIdx.x;
    int e = t * 4;
    if (e + 3 < E) {
        int4 d4 = *(const int4*)(col + e);
        int4 s4 = *(const int4*)(row + e);
        int p0 = atomicAdd(&cursor[d4.x], 1);
        int p1 = atomicAdd(&cursor[d4.y], 1);
        int p2 = atomicAdd(&cursor[d4.z], 1);
        int p3 = atomicAdd(&cursor[d4.w], 1);
        if (p0 < CAP) list[d4.x * CAP + p0] = (unsigned short)s4.x;
        if (p1 < CAP) list[d4.y * CAP + p1] = (unsigned short)s4.y;
        if (p2 < CAP) list[d4.z * CAP + p2] = (unsigned short)s4.z;
        if (p3 < CAP) list[d4.w * CAP + p3] = (unsigned short)s4.w;
    } else {
        for (; e < E; ++e) {
            int d = col[e];
            int p = atomicAdd(&cursor[d], 1);
            if (p < CAP) list[d * CAP + p] = (unsigned short)row[e];
        }
    }
}

__global__ __launch_bounds__(128) void k_gemm(const float* __restrict__ x,
                                              const float* __restrict__ W,
                                              const int* __restrict__ cursor,
                                              unsigned short* __restrict__ g, int N) {
    __shared__ float xs[NPBT][C];
    int n0 = blockIdx.x * NPBT;
    int o = threadIdx.x;
    const float4 z4 = {0.f, 0.f, 0.f, 0.f};
    for (int qi = o; qi < NPBT * C / 4; qi += 128) {
        int nd = qi >> 5, c4 = qi & 31;
        int n = n0 + nd;
        ((float4*)xs)[qi] = (n < N) ? ((const float4*)x)[(size_t)n * 32 + c4] : z4;
    }
    __syncthreads();
    float acc[NPBT];
#pragma unroll
    for (int nd = 0; nd < NPBT; ++nd) acc[nd] = 0.0f;
    const float4* Wr = (const float4*)(W + (size_t)o * C);
#pragma unroll 8
    for (int i = 0; i < C / 4; ++i) {
        float4 w = Wr[i];
#pragma unroll
        for (int nd = 0; nd < NPBT; ++nd) {
            float4 xv = *(const float4*)&xs[nd][i * 4];
            acc[nd] += w.x * xv.x + w.y * xv.y + w.z * xv.z + w.w * xv.w;
        }
    }
    for (int nd = 0; nd < NPBT; ++nd) {
        int n = n0 + nd;
        if (n < N) {
            float dv = 1.0f / sqrtf((float)(cursor[n] + 1));
            g[(size_t)n * C + o] = f2bf(acc[nd] * dv);
        }
    }
}

__global__ __launch_bounds__(256) void k_agg(const unsigned short* __restrict__ list,
                                             const int* __restrict__ cursor,
                                             const unsigned* __restrict__ gb,
                                             const float* __restrict__ b,
                                             float* __restrict__ out, int N) {
    int wv = (blockIdx.x * blockDim.x + threadIdx.x) >> 6;
    if (wv >= N) return;
    int lane = threadIdx.x & 63;
    int d = wv;
    int deg = cursor[d];
    float dv = 1.0f / sqrtf((float)(deg + 1));
    int cnt = (deg < CAP) ? deg : CAP;
    const unsigned short* lp = list + (size_t)d * CAP;
    unsigned sv = gb[(size_t)d * 64 + lane];
    float2 acc;
    acc.x = __uint_as_float(sv << 16);
    acc.y = __uint_as_float(sv & 0xffff0000u);
#define UNPACK_ADD(V) { acc.x += __uint_as_float((V) << 16); \
                        acc.y += __uint_as_float((V) & 0xffff0000u); }
    int j = 0;
    for (; j + 8 <= cnt; j += 8) {
        uint4 q = *(const uint4*)(lp + j);
        unsigned s0 = q.x & 0xffffu, s1 = q.x >> 16;
        unsigned s2 = q.y & 0xffffu, s3 = q.y >> 16;
        unsigned s4 = q.z & 0xffffu, s5 = q.z >> 16;
        unsigned s6 = q.w & 0xffffu, s7 = q.w >> 16;
        unsigned v0 = gb[(size_t)s0 * 64 + lane];
        unsigned v1 = gb[(size_t)s1 * 64 + lane];
        unsigned v2 = gb[(size_t)s2 * 64 + lane];
        unsigned v3 = gb[(size_t)s3 * 64 + lane];
        unsigned v4 = gb[(size_t)s4 * 64 + lane];
        unsigned v5 = gb[(size_t)s5 * 64 + lane];
        unsigned v6 = gb[(size_t)s6 * 64 + lane];
        unsigned v7 = gb[(size_t)s7 * 64 + lane];
        UNPACK_ADD(v0) UNPACK_ADD(v1) UNPACK_ADD(v2) UNPACK_ADD(v3)
        UNPACK_ADD(v4) UNPACK_ADD(v5) UNPACK_ADD(v6) UNPACK_ADD(v7)
    }
    for (; j < cnt; ++j) {
        unsigned s = lp[j];
        unsigned v = gb[(size_t)s * 64 + lane];
        UNPACK_ADD(v)
    }
#undef UNPACK_ADD
    int c2 = lane * 2;
    float2 bb = *(const float2*)(b + c2);
    float2 o;
    o.x = dv * acc.x + bb.x;
    o.y = dv * acc.y + bb.y;
    *(float2*)(out + (size_t)d * C + c2) = o;
}

extern "C" void kernel_launch(void* const* d_in, const int* in_sizes, int n_in,
                              void* d_out, int out_size, void* d_ws, size_t ws_size,
                              hipStream_t stream) {
    const float* x  = (const float*)d_in[0];
    const int*   ei = (const int*)d_in[1];
    const float* W  = (const float*)d_in[2];
    const float* b  = (const float*)d_in[3];
    float* out = (float*)d_out;

    int N = in_sizes[0] / C;   // 10000
    int E = in_sizes[1] / 2;   // 640000
    const int* row = ei;       // sources
    const int* col = ei + E;   // destinations

    // ws: [cursor: N i32][tileCtr: 16 i32][list: N*CAP u16][g: N*C bf16]
    int* cursor = (int*)d_ws;
    int* tileCtr = cursor + N;
    unsigned short* list = (unsigned short*)(tileCtr + 16);
    unsigned short* g    = list + (size_t)N * CAP;

    void* args[] = {(void*)&x, (void*)&row, (void*)&col, (void*)&W, (void*)&b,
                    (void*)&cursor, (void*)&list, (void*)&g, (void*)&tileCtr,
                    (void*)&out, (void*)&N, (void*)&E};
    hipError_t err = hipLaunchCooperativeKernel((const void*)k_fused, dim3(GRID), dim3(TPB),
                                                args, 0, stream);
    if (err != hipSuccess) {
        // fallback: proven 4-dispatch pipeline
        hipMemsetAsync(cursor, 0, (size_t)N * sizeof(int), stream);
        k_fill<<<(E / 4 + 255) / 256, 256, 0, stream>>>(row, col, cursor, list, E);
        k_gemm<<<(N + NPBT - 1) / NPBT, 128, 0, stream>>>(x, W, cursor, g, N);
        k_agg<<<((size_t)N * 64 + 255) / 256, 256, 0, stream>>>(list, cursor,
                                                                (const unsigned*)g, b, out, N);
    }
}

// Round 10
// 152.696 us; speedup vs baseline: 2.1685x; 2.1685x over previous
//
#include <hip/hip_runtime.h>

#define C     128   // channels
#define CAP   128   // per-dest segment capacity (deg mean 64, sigma 8 -> 8 sigma)
#define NPBT  16    // nodes per gemm tile
#define TPB   256

__device__ inline unsigned short f2bf(float v) {  // RNE float->bf16
    unsigned u = __float_as_uint(v);
    u = (u + 0x7fffu + ((u >> 16) & 1u)) >> 16;
    return (unsigned short)u;
}

// ==== fused fill || gemm: independent work, role by block parity ====
// fill : cursor[d]++ (== in-degree) and list[d*CAP + slot] = src   (atomic pipe)
// gemm : g[n][o] = bf16(x[n] . W[o])   -- UNSCALED; dis applied in agg (VALU/LDS)
__global__ __launch_bounds__(TPB) void k_fillgemm(
    const float* __restrict__ x, const int* __restrict__ row, const int* __restrict__ col,
    const float* __restrict__ W, int* __restrict__ cursor,
    unsigned short* __restrict__ list, unsigned short* __restrict__ g,
    int N, int E, int nfill, int ngemm) {
    __shared__ float xs[NPBT][C];  // 8 KB (gemm role only)
    int b = blockIdx.x;
    int tid = threadIdx.x;
    int m = 2 * (nfill < ngemm ? nfill : ngemm);
    int role, id;
    if (b < m) { role = b & 1; id = b >> 1; }
    else { role = (nfill > ngemm) ? 0 : 1; id = (m >> 1) + (b - m); }

    if (role == 0) {
        // ---- fill: one int4 quad per thread ----
        int q = id * TPB + tid;
        int e = q * 4;
        if (e + 3 < E) {
            int4 d4 = *(const int4*)(col + e);
            int4 s4 = *(const int4*)(row + e);
            int p0 = atomicAdd(&cursor[d4.x], 1);
            int p1 = atomicAdd(&cursor[d4.y], 1);
            int p2 = atomicAdd(&cursor[d4.z], 1);
            int p3 = atomicAdd(&cursor[d4.w], 1);
            if (p0 < CAP) list[d4.x * CAP + p0] = (unsigned short)s4.x;
            if (p1 < CAP) list[d4.y * CAP + p1] = (unsigned short)s4.y;
            if (p2 < CAP) list[d4.z * CAP + p2] = (unsigned short)s4.z;
            if (p3 < CAP) list[d4.w * CAP + p3] = (unsigned short)s4.w;
        } else {
            for (; e < E && e < q * 4 + 4; ++e) {
                int d = col[e];
                int p = atomicAdd(&cursor[d], 1);
                if (p < CAP) list[d * CAP + p] = (unsigned short)row[e];
            }
        }
    } else {
        // ---- gemm: 16-node tile, 256 threads = 2 halves x 128 channels ----
        int half = tid >> 7;
        int o = tid & 127;
        int n0 = id * NPBT;
        const float4 z4 = {0.f, 0.f, 0.f, 0.f};
        for (int qi = tid; qi < NPBT * C / 4; qi += TPB) {
            int nd = qi >> 5, c4 = qi & 31;
            int n = n0 + nd;
            ((float4*)xs)[qi] = (n < N) ? ((const float4*)x)[(size_t)n * 32 + c4] : z4;
        }
        __syncthreads();
        float acc[8];
#pragma unroll
        for (int nd = 0; nd < 8; ++nd) acc[nd] = 0.0f;
        const float4* Wr = (const float4*)(W + (size_t)o * C);
        int nb = half * 8;
#pragma unroll 8
        for (int i = 0; i < C / 4; ++i) {
            float4 w = Wr[i];
#pragma unroll
            for (int nd = 0; nd < 8; ++nd) {
                float4 xv = *(const float4*)&xs[nb + nd][i * 4];
                acc[nd] += w.x * xv.x + w.y * xv.y + w.z * xv.z + w.w * xv.w;
            }
        }
#pragma unroll
        for (int nd = 0; nd < 8; ++nd) {
            int n = n0 + nb + nd;
            if (n < N) g[(size_t)n * C + o] = f2bf(acc[nd]);  // unscaled
        }
    }
}

// ==== agg: wave per dest; acc = g[d]*dis[d] + sum g[s]*dis[s]; out = dis[d]*acc + b ====
__global__ __launch_bounds__(256) void k_agg(const unsigned short* __restrict__ list,
                                             const int* __restrict__ cursor,
                                             const unsigned* __restrict__ gb,
                                             const float* __restrict__ b,
                                             float* __restrict__ out, int N) {
    int wv = (blockIdx.x * blockDim.x + threadIdx.x) >> 6;
    if (wv >= N) return;
    int lane = threadIdx.x & 63;
    int d = wv;
    int deg = cursor[d];
    float dvd = 1.0f / sqrtf((float)(deg + 1));
    int cnt = (deg < CAP) ? deg : CAP;
    const unsigned short* lp = list + (size_t)d * CAP;

    unsigned sv = gb[(size_t)d * 64 + lane];  // self-loop row
    float2 acc;
    acc.x = __uint_as_float(sv << 16) * dvd;
    acc.y = __uint_as_float(sv & 0xffff0000u) * dvd;

#define FMA_ADD(V, DV) { acc.x += __uint_as_float((V) << 16) * (DV); \
                         acc.y += __uint_as_float((V) & 0xffff0000u) * (DV); }
    int j = 0;
    for (; j + 8 <= cnt; j += 8) {
        uint4 q = *(const uint4*)(lp + j);
        unsigned s0 = q.x & 0xffffu, s1 = q.x >> 16;
        unsigned s2 = q.y & 0xffffu, s3 = q.y >> 16;
        unsigned s4 = q.z & 0xffffu, s5 = q.z >> 16;
        unsigned s6 = q.w & 0xffffu, s7 = q.w >> 16;
        int c0 = cursor[s0], c1 = cursor[s1], c2_ = cursor[s2], c3 = cursor[s3];
        int c4 = cursor[s4], c5 = cursor[s5], c6 = cursor[s6], c7 = cursor[s7];
        unsigned v0 = gb[(size_t)s0 * 64 + lane];
        unsigned v1 = gb[(size_t)s1 * 64 + lane];
        unsigned v2 = gb[(size_t)s2 * 64 + lane];
        unsigned v3 = gb[(size_t)s3 * 64 + lane];
        unsigned v4 = gb[(size_t)s4 * 64 + lane];
        unsigned v5 = gb[(size_t)s5 * 64 + lane];
        unsigned v6 = gb[(size_t)s6 * 64 + lane];
        unsigned v7 = gb[(size_t)s7 * 64 + lane];
        float d0 = 1.0f / sqrtf((float)(c0 + 1));
        float d1 = 1.0f / sqrtf((float)(c1 + 1));
        float d2 = 1.0f / sqrtf((float)(c2_ + 1));
        float d3 = 1.0f / sqrtf((float)(c3 + 1));
        float d4 = 1.0f / sqrtf((float)(c4 + 1));
        float d5 = 1.0f / sqrtf((float)(c5 + 1));
        float d6 = 1.0f / sqrtf((float)(c6 + 1));
        float d7 = 1.0f / sqrtf((float)(c7 + 1));
        FMA_ADD(v0, d0) FMA_ADD(v1, d1) FMA_ADD(v2, d2) FMA_ADD(v3, d3)
        FMA_ADD(v4, d4) FMA_ADD(v5, d5) FMA_ADD(v6, d6) FMA_ADD(v7, d7)
    }
    for (; j < cnt; ++j) {
        unsigned s = lp[j];
        unsigned v = gb[(size_t)s * 64 + lane];
        float dv = 1.0f / sqrtf((float)(cursor[s] + 1));
        FMA_ADD(v, dv)
    }
#undef FMA_ADD

    int c2 = lane * 2;
    float2 bb = *(const float2*)(b + c2);
    float2 o;
    o.x = dvd * acc.x + bb.x;
    o.y = dvd * acc.y + bb.y;
    *(float2*)(out + (size_t)d * C + c2) = o;
}

extern "C" void kernel_launch(void* const* d_in, const int* in_sizes, int n_in,
                              void* d_out, int out_size, void* d_ws, size_t ws_size,
                              hipStream_t stream) {
    const float* x  = (const float*)d_in[0];
    const int*   ei = (const int*)d_in[1];
    const float* W  = (const float*)d_in[2];
    const float* b  = (const float*)d_in[3];
    float* out = (float*)d_out;

    int N = in_sizes[0] / C;   // 10000
    int E = in_sizes[1] / 2;   // 640000
    const int* row = ei;       // sources
    const int* col = ei + E;   // destinations

    // ws: [cursor: N i32][list: N*CAP u16][g: N*C bf16]
    int* cursor = (int*)d_ws;
    unsigned short* list = (unsigned short*)(cursor + N);
    unsigned short* g    = list + (size_t)N * CAP;

    int nfill = ((E + 3) / 4 + TPB - 1) / TPB;   // 625
    int ngemm = (N + NPBT - 1) / NPBT;           // 625

    hipMemsetAsync(cursor, 0, (size_t)N * sizeof(int), stream);
    k_fillgemm<<<nfill + ngemm, TPB, 0, stream>>>(x, row, col, W, cursor, list, g,
                                                  N, E, nfill, ngemm);
    k_agg<<<((size_t)N * 64 + 255) / 256, 256, 0, stream>>>(list, cursor,
                                                            (const unsigned*)g, b, out, N);
}